// Round 8
// baseline (355.841 us; speedup 1.0000x reference)
//
#include <hip/hip_runtime.h>
#include <cstdint>
#include <cstddef>

#define D_MODEL 1024
#define SEQ 1024
#define BATCH 4
#define NHEAD 16
#define HDIM 64
#define ROWS (BATCH*SEQ)   // 4096

typedef unsigned short u16;
typedef __attribute__((ext_vector_type(4))) unsigned short u16x4;
typedef __attribute__((ext_vector_type(8))) unsigned short u16x8;
typedef __attribute__((ext_vector_type(8))) __bf16 bf16x8v;
typedef __attribute__((ext_vector_type(4))) float f32x4;

__device__ inline u16 f2bf(float f){
  union{float f; unsigned u;} c; c.f = f;
  unsigned r = c.u + 0x7FFFu + ((c.u>>16)&1u);
  return (u16)(r>>16);
}
__device__ inline float bf2f(u16 s){
  union{unsigned u; float f;} c; c.u = ((unsigned)s)<<16; return c.f;
}
__device__ inline float gelu_f(float x){ return 0.5f*x*(1.f+erff(x*0.7071067811865475f)); }

__device__ __forceinline__ void gload_lds16(const void* g, void* l){
  __builtin_amdgcn_global_load_lds(
    (const __attribute__((address_space(1))) unsigned int*)g,
    (__attribute__((address_space(3))) unsigned int*)l, 16, 0, 0);
}

// ---------------- elementwise convert f32 -> bf16 -------------------
__global__ __launch_bounds__(256) void convert_bf(const float* __restrict__ in, u16* __restrict__ out){
  size_t idx = (size_t)blockIdx.x*256 + threadIdx.x;
  f32x4 v = *(const f32x4*)(in + idx*4);
  u16x4 o = { f2bf(v.x), f2bf(v.y), f2bf(v.z), f2bf(v.w) };
  *(u16x4*)(out + idx*4) = o;
}

struct C3 { const float* src[3]; u16* dst[3]; };
__global__ __launch_bounds__(256) void convert_w3(C3 p){
  int z = blockIdx.z;
  size_t idx = (size_t)blockIdx.x*256 + threadIdx.x;
  f32x4 v = *(const f32x4*)(p.src[z] + idx*4);
  u16x4 o = { f2bf(v.x), f2bf(v.y), f2bf(v.z), f2bf(v.w) };
  *(u16x4*)(p.dst[z] + idx*4) = o;
}

// ---------------- tiled transpose + convert: W[K][N] -> WT[N][K] bf16 ----
__global__ __launch_bounds__(256) void transpose_conv(const float* __restrict__ W, u16* __restrict__ WT, int K, int N){
  __shared__ float tile[32][33];
  int n0 = blockIdx.x*32, k0 = blockIdx.y*32;
  int tx = threadIdx.x & 31, ty = threadIdx.x >> 5;
  #pragma unroll
  for (int i=0;i<4;i++){
    int r = ty + i*8;
    tile[r][tx] = W[(size_t)(k0+r)*N + n0 + tx];
  }
  __syncthreads();
  #pragma unroll
  for (int i=0;i<4;i++){
    int r = ty + i*8;
    WT[(size_t)(n0+r)*K + k0 + tx] = f2bf(tile[tx][r]);
  }
}

// --------- per-head transpose (batched): Wh[H][D][64] -> WT[(h*64+e)][D] --
struct H3 { const float* src[3]; u16* dst[3]; };
__global__ __launch_bounds__(256) void head_transpose3(H3 p){
  __shared__ float tile[32][33];
  int z = blockIdx.z; int which = z >> 4; int h = z & 15;
  const float* Wh = p.src[which];
  u16* WT = p.dst[which];
  int d0 = blockIdx.x*32, e0 = blockIdx.y*32;
  int tx = threadIdx.x & 31, ty = threadIdx.x >> 5;
  #pragma unroll
  for (int i=0;i<4;i++){
    int r = ty + i*8;
    tile[r][tx] = Wh[(size_t)h*D_MODEL*HDIM + (size_t)(d0+r)*HDIM + e0 + tx];
  }
  __syncthreads();
  #pragma unroll
  for (int i=0;i<4;i++){
    int r = ty + i*8;
    WT[(size_t)(h*HDIM + e0 + r)*D_MODEL + d0 + tx] = f2bf(tile[tx][r]);
  }
}

// --------- combined bias: bc[z*1024 + h*64+e] = dot(bz, Whz[h][:][e]) + bhz
__global__ __launch_bounds__(64) void bias_comb(
  const float* bk, const float* bq, const float* bv,
  const float* Whq, const float* Whk, const float* Whv,
  const float* bhq, const float* bhk, const float* bhv, float* bc)
{
  int blk = blockIdx.x; int which = blk >> 4; int h = blk & 15; int e = threadIdx.x;
  const float* bvec = (which==0) ? bk : (which==1) ? bq : bv;
  const float* Wh   = (which==0) ? Whq : (which==1) ? Whk : Whv;
  const float* bh   = (which==0) ? bhq : (which==1) ? bhk : bhv;
  float s = bh[h*HDIM + e];
  const float* w = Wh + (size_t)h*D_MODEL*HDIM + e;
  for (int d=0; d<D_MODEL; ++d) s += bvec[d] * w[(size_t)d*HDIM];
  bc[which*1024 + h*HDIM + e] = s;
}

// =================== 256x256 8-phase GEMM (T2+T3+T4+T5) ===================
// BK=64, 8 waves (2M x 4N), LDS 2dbuf x 2half x [128][64] per operand.
// B halves persist in regs. modes: 1 = bf16 row-major stride N (+act);
// 2 = QKV fused: panel0->out, panel1->out+4M, panel2 transposed ->out+8M.
__global__ __launch_bounds__(512,2) void gemm256_8p(
  const u16* __restrict__ A, const u16* __restrict__ BT, const float* __restrict__ bias,
  u16* __restrict__ outB, int N, int K, int mode, int act)
{
  __shared__ __align__(16) u16 As[2][2][128*64];
  __shared__ __align__(16) u16 Bs[2][2][128*64];
  int t = threadIdx.x, lane = t&63, wid = t>>6;
  int wr = wid>>2, wc = wid&3;
  int fr = lane&15, kg = lane>>4;
  int gx = gridDim.x;
  int bid = blockIdx.y*gx + blockIdx.x;
  int nwg = gx*gridDim.y;
  int cpx = nwg>>3;
  int sw = (bid&7)*cpx + (bid>>3);
  int tc = sw % gx, tr = sw / gx;

  const u16* Abase = A  + (size_t)tr*256*K;
  const u16* Bbase = BT + (size_t)tc*256*K;
  int srow = lane>>3, sch8 = lane&7;

  f32x4 acc[8][4];
  #pragma unroll
  for (int m=0;m<8;m++)
    #pragma unroll
    for (int n=0;n<4;n++) acc[m][n] = (f32x4)0.f;

  bf16x8v af[2][4], bv0[2][2], bv1[2][2];

  #define STAGE_A8(buf,h,kt) { _Pragma("unroll") for (int li=0;li<2;li++){ \
    int sr = (wid*2+li)*8 + srow; \
    int gr = ((sr>>6)<<7) + (h)*64 + (sr&63); \
    int sc = sch8 ^ (sr&7); \
    gload_lds16(Abase + (size_t)gr*K + (size_t)(kt)*64 + sc*8, &As[buf][h][(wid*2+li)*512]); } }
  #define STAGE_B8(buf,h,kt) { _Pragma("unroll") for (int li=0;li<2;li++){ \
    int sr = (wid*2+li)*8 + srow; \
    int gc = ((sr>>5)<<6) + (h)*32 + (sr&31); \
    int sc = sch8 ^ (sr&7); \
    gload_lds16(Bbase + (size_t)gc*K + (size_t)(kt)*64 + sc*8, &Bs[buf][h][(wid*2+li)*512]); } }
  #define LDA8(buf,h) { _Pragma("unroll") for (int ks=0;ks<2;ks++) _Pragma("unroll") for (int mf=0;mf<4;mf++){ \
    int r = wr*64 + mf*16 + fr; \
    af[ks][mf] = *(const bf16x8v*)&As[buf][h][r*64 + (((kg+4*ks)^(r&7)))*8]; } }
  #define LDB8(buf,h,dst) { _Pragma("unroll") for (int ks=0;ks<2;ks++) _Pragma("unroll") for (int nf=0;nf<2;nf++){ \
    int r = wc*32 + nf*16 + fr; \
    dst[ks][nf] = *(const bf16x8v*)&Bs[buf][h][r*64 + (((kg+4*ks)^(r&7)))*8]; } }
  #define MM8(mq,nq,bv) { asm volatile("s_waitcnt lgkmcnt(0)" ::: "memory"); \
    __builtin_amdgcn_s_setprio(1); \
    _Pragma("unroll") for (int ks=0;ks<2;ks++) _Pragma("unroll") for (int mf=0;mf<4;mf++) _Pragma("unroll") for (int nf=0;nf<2;nf++) \
      acc[(mq)*4+mf][(nq)*2+nf] = __builtin_amdgcn_mfma_f32_16x16x32_bf16(af[ks][mf], bv[ks][nf], acc[(mq)*4+mf][(nq)*2+nf], 0,0,0); \
    __builtin_amdgcn_s_setprio(0); }
  #define BAR asm volatile("s_barrier" ::: "memory")

  int NT = K >> 6;
  STAGE_A8(0,0,0); STAGE_B8(0,0,0); STAGE_B8(0,1,0); STAGE_A8(0,1,0);
  asm volatile("s_waitcnt vmcnt(4)" ::: "memory");
  BAR;

  for (int kt=0; kt<NT; ++kt){
    int buf = kt&1, nb = buf^1;
    int pre = (kt+1 < NT);
    LDA8(buf,0); LDB8(buf,0,bv0);
    if (pre){ STAGE_A8(nb,0,kt+1); asm volatile("s_waitcnt vmcnt(4)" ::: "memory"); }
    else    {                      asm volatile("s_waitcnt vmcnt(2)" ::: "memory"); }
    BAR; MM8(0,0,bv0); BAR;
    LDB8(buf,1,bv1);
    if (pre){ STAGE_B8(nb,0,kt+1); asm volatile("s_waitcnt vmcnt(4)" ::: "memory"); }
    else    {                      asm volatile("s_waitcnt vmcnt(0)" ::: "memory"); }
    BAR; MM8(0,1,bv1); BAR;
    LDA8(buf,1);
    if (pre){ STAGE_B8(nb,1,kt+1); asm volatile("s_waitcnt vmcnt(6)" ::: "memory"); }
    BAR; MM8(1,1,bv1); BAR;
    if (pre){ STAGE_A8(nb,1,kt+1); asm volatile("s_waitcnt vmcnt(4)" ::: "memory"); }
    BAR; MM8(1,0,bv0); BAR;
  }

  int crow0 = tr*256 + wr*128;
  int ccol0 = tc*256 + wc*64;
  #pragma unroll
  for (int n=0;n<4;n++){
    int col = ccol0 + n*16 + fr;
    float bv = bias[col];
    #pragma unroll
    for (int m=0;m<8;m++){
      int rbase = crow0 + m*16 + kg*4;
      #pragma unroll
      for (int i=0;i<4;i++){
        float v = acc[m][n][i] + bv;
        if (act) v = gelu_f(v);
        int row = rbase + i;
        if (mode == 1){
          outB[(size_t)row*N + col] = f2bf(v);
        } else {
          int panel = col >> 10, c1 = col & 1023;
          if (panel < 2)
            outB[(size_t)panel*((size_t)ROWS*1024) + (size_t)row*1024 + c1] = f2bf(v);
          else {
            int b = row >> 10, s = row & 1023;
            int hh = c1 >> 6, e = c1 & 63;
            outB[(size_t)2*((size_t)ROWS*1024) + (((size_t)((b*NHEAD+hh)*HDIM+e))<<10) + s] = f2bf(v);
          }
        }
      }
    }
  }
}

// ============ 128x128 tile, BK=32, 4 waves, 3-buffer 2-deep pipeline ======
__device__ __forceinline__ void stage128(u16 (*As)[4096], u16 (*Bs)[4096], int b,
  const u16* Ab, const u16* Bb, int Kstride, int kt, int wid, int rr, int sch)
{
  #pragma unroll
  for (int c=0;c<2;c++){
    int reg = c*4 + wid;
    int row = reg*16 + rr;
    gload_lds16(Ab + (size_t)row*Kstride + kt*32 + sch*8, &As[b][reg*512]);
  }
  #pragma unroll
  for (int c=0;c<2;c++){
    int reg = c*4 + wid;
    int row = reg*16 + rr;
    gload_lds16(Bb + (size_t)row*Kstride + kt*32 + sch*8, &Bs[b][reg*512]);
  }
}

__device__ __forceinline__ void gemm128_core(u16 (*As)[4096], u16 (*Bs)[4096],
  const u16* __restrict__ A, const u16* __restrict__ BT, const float* __restrict__ bias,
  float* __restrict__ outF, u16* __restrict__ outB,
  int N, int Kstride, int kofs, int Ksub, int mode, int act, int addbias)
{
  int t = threadIdx.x, lane = t&63, wid = t>>6;
  int wr = wid>>1, wc = wid&1;
  int fr = lane&15, kg = lane>>4;
  int gx = gridDim.x;
  int bid = blockIdx.y*gx + blockIdx.x;
  int nwg = gx*gridDim.y;
  int cpx = nwg >> 3;
  int sw = (bid&7)*cpx + (bid>>3);
  int tc = sw % gx, tr = sw / gx;

  const u16* Ab = A  + (size_t)tr*128*Kstride + kofs;
  const u16* Bb = BT + (size_t)tc*128*Kstride + kofs;
  int rr = lane>>2, cc = lane&3;
  int sch = cc ^ ((rr>>1)&3);

  f32x4 acc[4][4];
  #pragma unroll
  for (int m=0;m<4;m++)
    #pragma unroll
    for (int n=0;n<4;n++) acc[m][n] = (f32x4)0.f;

  int NT = Ksub >> 5;

  stage128(As, Bs, 0, Ab, Bb, Kstride, 0, wid, rr, sch);
  stage128(As, Bs, 1, Ab, Bb, Kstride, 1, wid, rr, sch);
  int buf = 0;
  for (int kt=0; kt<NT; ++kt){
    if (kt+2 < NT){
      int nb = buf+2; if (nb>=3) nb-=3;
      stage128(As, Bs, nb, Ab, Bb, Kstride, kt+2, wid, rr, sch);
      asm volatile("s_waitcnt vmcnt(8)" ::: "memory");
    } else if (kt+1 < NT){
      asm volatile("s_waitcnt vmcnt(4)" ::: "memory");
    } else {
      asm volatile("s_waitcnt vmcnt(0)" ::: "memory");
    }
    asm volatile("s_barrier" ::: "memory");
    bf16x8v af[4], bfv[4];
    #pragma unroll
    for (int m=0;m<4;m++){
      int r = wr*64 + m*16 + fr;
      af[m] = *(const bf16x8v*)&As[buf][r*32 + (kg ^ ((r>>1)&3))*8];
    }
    #pragma unroll
    for (int n=0;n<4;n++){
      int r = wc*64 + n*16 + fr;
      bfv[n] = *(const bf16x8v*)&Bs[buf][r*32 + (kg ^ ((r>>1)&3))*8];
    }
    #pragma unroll
    for (int m=0;m<4;m++)
      #pragma unroll
      for (int n=0;n<4;n++)
        acc[m][n] = __builtin_amdgcn_mfma_f32_16x16x32_bf16(af[m], bfv[n], acc[m][n], 0,0,0);
    if (kt+1 < NT)
      asm volatile("s_barrier" ::: "memory");
    buf += 1; if (buf >= 3) buf = 0;
  }

  int crow0 = tr*128 + wr*64;
  int ccol0 = tc*128 + wc*64;
  #pragma unroll
  for (int n=0;n<4;n++){
    int col = ccol0 + n*16 + fr;
    float bv = addbias ? bias[col] : 0.f;
    #pragma unroll
    for (int m=0;m<4;m++){
      int rbase = crow0 + m*16 + kg*4;
      #pragma unroll
      for (int i=0;i<4;i++){
        float v = acc[m][n][i] + bv;
        if (act) v = gelu_f(v);
        int row = rbase + i;
        if (mode == 1){
          outB[(size_t)row*N + col] = f2bf(v);
        } else {
          outF[(size_t)row*1024 + col] = v;
        }
      }
    }
  }
}

// split-K (2-way): z selects K-half; fp32 partial panels; bias on z==0
__global__ __launch_bounds__(256) void g_gemm_sk(
  const u16* A, const u16* BT, const float* bias, float* outBase, int K)
{
  __shared__ __align__(16) u16 As[3][4096];
  __shared__ __align__(16) u16 Bs[3][4096];
  int z = blockIdx.z;
  int Ksub = K >> 1;
  gemm128_core(As, Bs, A, BT, bias, outBase + (size_t)z*ROWS*1024, nullptr,
               1024, K, z*Ksub, Ksub, 3, 0, z==0);
}

struct B3 { const u16* A[3]; const u16* BT[3]; u16* Cb[3]; };
__global__ __launch_bounds__(256) void g_gemm_b3(B3 p, const float* bias){
  __shared__ __align__(16) u16 As[3][4096];
  __shared__ __align__(16) u16 Bs[3][4096];
  int z = blockIdx.z;
  gemm128_core(As, Bs, p.A[z], p.BT[z], bias, nullptr, p.Cb[z],
               1024, 1024, 0, 1024, 1, 0, 0);
}

// ====== MFMA flash attention: double-buffered staging, 1 barrier/tile =====
// Block: one (b,h) x 64 q-rows, 4 waves x 16 rows. KV tile 64, LDS dbuf.
// STAGE(kt+1) issued before compute(kt); vmcnt(0)+barrier at tile end (T3).
// exp2-domain softmax + defer-max (T13, THR=8).
__global__ __launch_bounds__(256) void attn_mfma(const u16* __restrict__ Q, const u16* __restrict__ Km,
                                                 const u16* __restrict__ Vt, u16* __restrict__ O)
{
  __shared__ __align__(16) u16 Ks[2][64*64];
  __shared__ __align__(16) u16 Vs[2][64*64];
  __shared__ __align__(16) u16 Ps[4][16*64];
  int t = threadIdx.x, lane = t & 63, wid = t >> 6;
  int fr = lane & 15, kg = lane >> 4;
  int qt = blockIdx.x, h = blockIdx.y, b = blockIdx.z;
  const size_t qkbase = ((size_t)b*SEQ)*D_MODEL + (size_t)h*HDIM;
  const size_t vtb = ((size_t)(b*NHEAD + h))*HDIM*SEQ;

  int qrow = qt*64 + wid*16 + fr;
  bf16x8v aq0 = *(const bf16x8v*)(Q + qkbase + (size_t)qrow*D_MODEL + kg*8);
  bf16x8v aq1 = *(const bf16x8v*)(Q + qkbase + (size_t)qrow*D_MODEL + 32 + kg*8);

  f32x4 Oacc[4];
  #pragma unroll
  for (int n=0;n<4;n++) Oacc[n] = (f32x4)0.f;
  float m_run[4], l_run[4];
  #pragma unroll
  for (int i=0;i<4;i++){ m_run[i] = -3e38f; l_run[i] = 0.f; }

  int srow = lane >> 3;
  int sch  = (lane & 7) ^ srow;
  int x7 = fr & 7;
  const float CS = 0.03125f * 1.4426950408889634f;   // 1/sqrt(D) * log2(e)
  u16* Pw = &Ps[wid][0];

  #define ASTG(bf,kt) { _Pragma("unroll") for (int c=0;c<2;c++){ \
    int r0 = (wid*2 + c)*8; int rowk = r0 + srow; \
    gload_lds16(Km + qkbase + (size_t)((kt)*64 + rowk)*D_MODEL + sch*8, &Ks[bf][r0*64]); \
    gload_lds16(Vt + vtb + (size_t)rowk*SEQ + (kt)*64 + sch*8, &Vs[bf][r0*64]); } }

  ASTG(0,0);
  asm volatile("s_waitcnt vmcnt(0)" ::: "memory");
  __syncthreads();

  for (int kt = 0; kt < SEQ/64; ++kt){
    int bf = kt & 1;
    if (kt+1 < SEQ/64) ASTG(bf^1, kt+1);

    // S = Q K^T (exp2-domain scale applied after)
    f32x4 s4[4];
    #pragma unroll
    for (int n=0;n<4;n++){
      int r = n*16 + fr;
      bf16x8v k0 = *(const bf16x8v*)&Ks[bf][r*64 + ((kg  ) ^ x7)*8];
      bf16x8v k1 = *(const bf16x8v*)&Ks[bf][r*64 + ((4+kg) ^ x7)*8];
      f32x4 z = (f32x4)0.f;
      z = __builtin_amdgcn_mfma_f32_16x16x32_bf16(aq0, k0, z, 0,0,0);
      s4[n] = __builtin_amdgcn_mfma_f32_16x16x32_bf16(aq1, k1, z, 0,0,0);
    }
    #pragma unroll
    for (int n=0;n<4;n++) s4[n] *= CS;

    // online softmax (exp2 domain, defer-max)
    float mI[4];
    #pragma unroll
    for (int i=0;i<4;i++)
      mI[i] = fmaxf(fmaxf(s4[0][i], s4[1][i]), fmaxf(s4[2][i], s4[3][i]));
    #pragma unroll
    for (int off=1; off<16; off<<=1){
      #pragma unroll
      for (int i=0;i<4;i++) mI[i] = fmaxf(mI[i], __shfl_xor(mI[i], off));
    }
    float g = -3e38f;
    #pragma unroll
    for (int i=0;i<4;i++) g = fmaxf(g, mI[i] - m_run[i]);
    if (__any(g > 8.f)){
      #pragma unroll
      for (int i=0;i<4;i++){
        float mn = fmaxf(m_run[i], mI[i]);
        float sc = exp2f(m_run[i] - mn);
        m_run[i] = mn;
        l_run[i] *= sc;
        #pragma unroll
        for (int n=0;n<4;n++) Oacc[n][i] *= sc;
      }
    }
    float ls[4] = {0.f,0.f,0.f,0.f};
    #pragma unroll
    for (int n=0;n<4;n++){
      int chunk = n*2 + (fr>>3);
      #pragma unroll
      for (int i=0;i<4;i++){
        float pv = exp2f(s4[n][i] - m_run[i]);
        ls[i] += pv;
        int row = kg*4 + i;
        Pw[row*64 + (chunk ^ (row&7))*8 + (fr&7)] = f2bf(pv);
      }
    }
    #pragma unroll
    for (int off=1; off<16; off<<=1){
      #pragma unroll
      for (int i=0;i<4;i++) ls[i] += __shfl_xor(ls[i], off);
    }
    #pragma unroll
    for (int i=0;i<4;i++) l_run[i] += ls[i];
    asm volatile("s_waitcnt lgkmcnt(0)" ::: "memory");

    // O += P V
    bf16x8v ap0 = *(const bf16x8v*)&Pw[fr*64 + ((kg  ) ^ x7)*8];
    bf16x8v ap1 = *(const bf16x8v*)&Pw[fr*64 + ((4+kg) ^ x7)*8];
    #pragma unroll
    for (int n2=0;n2<4;n2++){
      int r = n2*16 + fr;
      bf16x8v v0 = *(const bf16x8v*)&Vs[bf][r*64 + ((kg  ) ^ x7)*8];
      bf16x8v v1 = *(const bf16x8v*)&Vs[bf][r*64 + ((4+kg) ^ x7)*8];
      Oacc[n2] = __builtin_amdgcn_mfma_f32_16x16x32_bf16(ap0, v0, Oacc[n2], 0,0,0);
      Oacc[n2] = __builtin_amdgcn_mfma_f32_16x16x32_bf16(ap1, v1, Oacc[n2], 0,0,0);
    }
    asm volatile("s_waitcnt vmcnt(0)" ::: "memory");
    __syncthreads();
  }

  float inv[4];
  #pragma unroll
  for (int i=0;i<4;i++) inv[i] = 1.f / l_run[i];
  #pragma unroll
  for (int n2=0;n2<4;n2++){
    #pragma unroll
    for (int i=0;i<4;i++){
      int row = qt*64 + wid*16 + kg*4 + i;
      O[qkbase + (size_t)row*D_MODEL + n2*16 + fr] = f2bf(Oacc[n2][i]*inv[i]);
    }
  }
}

// -------- residual(3-way) + LayerNorm: v = A + B + C; LN(v) --------------
__global__ __launch_bounds__(256) void ln_sum3(const float* __restrict__ A, const float* __restrict__ B,
   const float* __restrict__ C, const float* __restrict__ gamma, const float* __restrict__ beta,
   float* __restrict__ Of, u16* __restrict__ Ob)
{
  int row = blockIdx.x, t = threadIdx.x;
  size_t base = (size_t)row*D_MODEL + t*4;
  f32x4 v = *(const f32x4*)(A + base);
  v += *(const f32x4*)(B + base);
  v += *(const f32x4*)(C + base);
  float s = v.x+v.y+v.z+v.w;
  float q = v.x*v.x+v.y*v.y+v.z*v.z+v.w*v.w;
  #pragma unroll
  for (int off=1; off<64; off<<=1){ s += __shfl_xor(s,off); q += __shfl_xor(q,off); }
  __shared__ float red[8];
  int wid = t>>6;
  if ((t&63)==0){ red[wid] = s; red[wid+4] = q; }
  __syncthreads();
  s = red[0]+red[1]+red[2]+red[3];
  q = red[4]+red[5]+red[6]+red[7];
  float mu = s*(1.f/1024.f);
  float var = q*(1.f/1024.f) - mu*mu;
  float rs = rsqrtf(var + 1e-5f);
  f32x4 g4 = *(const f32x4*)(gamma + t*4);
  f32x4 b4 = *(const f32x4*)(beta + t*4);
  f32x4 o;
  o.x = (v.x-mu)*rs*g4.x + b4.x;
  o.y = (v.y-mu)*rs*g4.y + b4.y;
  o.z = (v.z-mu)*rs*g4.z + b4.z;
  o.w = (v.w-mu)*rs*g4.w + b4.w;
  if (Of) *(f32x4*)(Of + base) = o;
  if (Ob){
    u16x4 ob = { f2bf(o.x), f2bf(o.y), f2bf(o.z), f2bf(o.w) };
    *(u16x4*)(Ob + base) = ob;
  }
}

extern "C" void kernel_launch(void* const* d_in, const int* in_sizes, int n_in,
                              void* d_out, int out_size, void* d_ws, size_t ws_size,
                              hipStream_t stream)
{
  const float* x    = (const float*)d_in[0];
  const float* Wk   = (const float*)d_in[1];
  const float* bk   = (const float*)d_in[2];
  const float* Wq   = (const float*)d_in[3];
  const float* bq   = (const float*)d_in[4];
  const float* Wv   = (const float*)d_in[5];
  const float* bv   = (const float*)d_in[6];
  const float* Whq  = (const float*)d_in[7];
  const float* bhq  = (const float*)d_in[8];
  const float* Whk  = (const float*)d_in[9];
  const float* bhk  = (const float*)d_in[10];
  const float* Whv  = (const float*)d_in[11];
  const float* bhv  = (const float*)d_in[12];
  const float* Wo   = (const float*)d_in[13];
  const float* bo   = (const float*)d_in[14];
  const float* W1   = (const float*)d_in[15];
  const float* b1   = (const float*)d_in[16];
  const float* W2   = (const float*)d_in[17];
  const float* b2   = (const float*)d_in[18];
  const float* gamma= (const float*)d_in[19];
  const float* beta = (const float*)d_in[20];

  char* ws = (char*)d_ws;
  const size_t MB_ = 1024*1024;
  u16* Wkb  = (u16*)(ws + 0*MB_);    // Wk bf16 row-major (no transpose)
  u16* Wqb  = (u16*)(ws + 2*MB_);
  u16* Wvb  = (u16*)(ws + 4*MB_);
  u16* WhqT = (u16*)(ws + 6*MB_);
  u16* WhkT = (u16*)(ws + 8*MB_);
  u16* WhvT = (u16*)(ws + 10*MB_);
  u16* WoT  = (u16*)(ws + 12*MB_);
  u16* W1T  = (u16*)(ws + 14*MB_);   // [4096][1024]
  u16* W2T  = (u16*)(ws + 22*MB_);   // [1024][4096]
  u16* xb   = (u16*)(ws + 30*MB_);   // 8MB
  u16* WcT  = (u16*)(ws + 38*MB_);   // 3 panels x 2MB: WcqT, WckT, WcvT
  float* bc = (float*)(ws + 44*MB_); // 3072 floats
  u16* qb   = (u16*)(ws + 46*MB_);   // qkv fused out: qb 46, kb 54, vt 62
  u16* kb   = (u16*)(ws + 54*MB_);
  u16* vt   = (u16*)(ws + 62*MB_);
  u16* Ob   = (u16*)(ws + 70*MB_);
  float* Pa = (float*)(ws + 78*MB_); // 32MB split-K partials (Wo, then FFN2)
  float* Pb = (float*)(ws + 94*MB_);
  float* r1f = (float*)(ws + 110*MB_);
  u16*  r1b  = (u16*)(ws + 38*MB_);  // reuses WcT+bc (dead after p_fused)
  u16*  ff1b = (u16*)(ws + 46*MB_);  // 32MB, reuses qb..Ob (dead after Wo)

  dim3 tb(256);

  // ---- prep ----
  convert_bf<<<dim3(ROWS*D_MODEL/4/256), tb, 0, stream>>>(x, xb);
  C3 cw; cw.src[0]=Wk; cw.src[1]=Wq; cw.src[2]=Wv;
  cw.dst[0]=Wkb; cw.dst[1]=Wqb; cw.dst[2]=Wvb;
  convert_w3<<<dim3(1024,1,3), tb, 0, stream>>>(cw);
  H3 hh; hh.src[0]=Whq; hh.src[1]=Whk; hh.src[2]=Whv;
  hh.dst[0]=WhqT; hh.dst[1]=WhkT; hh.dst[2]=WhvT;
  head_transpose3<<<dim3(32,2,48), tb, 0, stream>>>(hh);
  transpose_conv<<<dim3(32,32),  tb, 0, stream>>>(Wo, WoT, 1024, 1024);
  transpose_conv<<<dim3(128,32), tb, 0, stream>>>(W1, W1T, 1024, 4096);
  transpose_conv<<<dim3(32,128), tb, 0, stream>>>(W2, W2T, 4096, 1024);
  bias_comb<<<dim3(48), dim3(64), 0, stream>>>(bk,bq,bv, Whq,Whk,Whv, bhq,bhk,bhv, bc);

  // ---- weight combine: WcT[z] = Wh[z]^T · Wouter[z]^T  (z=q,k,v paths) ----
  B3 cmb;
  cmb.A[0]=WhqT; cmb.A[1]=WhkT; cmb.A[2]=WhvT;
  cmb.BT[0]=Wkb; cmb.BT[1]=Wqb; cmb.BT[2]=Wvb;
  cmb.Cb[0]=WcT; cmb.Cb[1]=WcT+1048576; cmb.Cb[2]=WcT+2097152;
  g_gemm_b3<<<dim3(8,8,3), tb, 0, stream>>>(cmb, bk);

  // ---- fused QKV projection: x @ [Wcq|Wck|Wcv] + bc -> qb, kb, vt ----
  gemm256_8p<<<dim3(12,16), dim3(512), 0, stream>>>(xb, WcT, bc, qb, 3072, 1024, 2, 0);

  // ---- attention ----
  attn_mfma<<<dim3(16,16,4), tb, 0, stream>>>(qb, kb, vt, Ob);

  // ---- Wo: split-K x2 -> fp32 partials Pa,Pb ----
  g_gemm_sk<<<dim3(8,32,2), tb, 0, stream>>>(Ob, WoT, bo, Pa, 1024);
  ln_sum3<<<dim3(4096), tb, 0, stream>>>(x, Pa, Pb, gamma, beta, r1f, r1b);
  // ---- FFN1 (gelu) ----
  gemm256_8p<<<dim3(16,16), dim3(512), 0, stream>>>(r1b, W1T, b1, ff1b, 4096, 1024, 1, 1);
  // ---- FFN2: split-K x2 -> Pa,Pb ----
  g_gemm_sk<<<dim3(8,32,2), tb, 0, stream>>>(ff1b, W2T, b2, Pa, 4096);
  ln_sum3<<<dim3(4096), tb, 0, stream>>>(r1f, Pa, Pb, gamma, beta, (float*)d_out, nullptr);

  (void)in_sizes; (void)n_in; (void)out_size; (void)ws_size;
}

// Round 9
// 332.967 us; speedup vs baseline: 1.0687x; 1.0687x over previous
//
#include <hip/hip_runtime.h>
#include <cstdint>
#include <cstddef>

#define D_MODEL 1024
#define SEQ 1024
#define BATCH 4
#define NHEAD 16
#define HDIM 64
#define ROWS (BATCH*SEQ)   // 4096

typedef unsigned short u16;
typedef __attribute__((ext_vector_type(4))) unsigned short u16x4;
typedef __attribute__((ext_vector_type(8))) unsigned short u16x8;
typedef __attribute__((ext_vector_type(8))) __bf16 bf16x8v;
typedef __attribute__((ext_vector_type(4))) float f32x4;

__device__ inline u16 f2bf(float f){
  union{float f; unsigned u;} c; c.f = f;
  unsigned r = c.u + 0x7FFFu + ((c.u>>16)&1u);
  return (u16)(r>>16);
}
__device__ inline float bf2f(u16 s){
  union{unsigned u; float f;} c; c.u = ((unsigned)s)<<16; return c.f;
}
__device__ inline float gelu_f(float x){ return 0.5f*x*(1.f+erff(x*0.7071067811865475f)); }

__device__ __forceinline__ void gload_lds16(const void* g, void* l){
  __builtin_amdgcn_global_load_lds(
    (const __attribute__((address_space(1))) unsigned int*)g,
    (__attribute__((address_space(3))) unsigned int*)l, 16, 0, 0);
}

// -------- merged convert f32->bf16: x (4M) + Wk,Wq,Wv (1M each) ----------
struct C4 { const float* src[4]; u16* dst[4]; };
__global__ __launch_bounds__(256) void convert4(C4 p){
  int bid = blockIdx.x;
  int which, off;
  if (bid < 4096){ which = 0; off = bid; }
  else { which = 1 + ((bid-4096) >> 10); off = (bid-4096) & 1023; }
  size_t idx = (size_t)off*256 + threadIdx.x;
  f32x4 v = *(const f32x4*)(p.src[which] + idx*4);
  u16x4 o = { f2bf(v.x), f2bf(v.y), f2bf(v.z), f2bf(v.w) };
  *(u16x4*)(p.dst[which] + idx*4) = o;
}

// -------- merged transpose+convert: Wo, W1, W2 ---------------------------
struct T3 { const float* W[3]; u16* WT[3]; };
__global__ __launch_bounds__(256) void transpose3(T3 p){
  __shared__ float tile[32][33];
  int bid = blockIdx.x;
  int which, bx, by, K, N;
  if (bid < 1024){ which=0; K=1024; N=1024; bx=bid&31;  by=bid>>5; }
  else if (bid < 5120){ int i=bid-1024; which=1; K=1024; N=4096; bx=i&127; by=i>>7; }
  else { int i=bid-5120; which=2; K=4096; N=1024; bx=i&31; by=i>>5; }
  const float* W = p.W[which];
  u16* WT = p.WT[which];
  int n0 = bx*32, k0 = by*32;
  int tx = threadIdx.x & 31, ty = threadIdx.x >> 5;
  #pragma unroll
  for (int i=0;i<4;i++){
    int r = ty + i*8;
    tile[r][tx] = W[(size_t)(k0+r)*N + n0 + tx];
  }
  __syncthreads();
  #pragma unroll
  for (int i=0;i<4;i++){
    int r = ty + i*8;
    WT[(size_t)(n0+r)*K + k0 + tx] = f2bf(tile[tx][r]);
  }
}

// --------- per-head transpose (batched): Wh[H][D][64] -> WT[(h*64+e)][D] --
struct H3 { const float* src[3]; u16* dst[3]; };
__global__ __launch_bounds__(256) void head_transpose3(H3 p){
  __shared__ float tile[32][33];
  int z = blockIdx.z; int which = z >> 4; int h = z & 15;
  const float* Wh = p.src[which];
  u16* WT = p.dst[which];
  int d0 = blockIdx.x*32, e0 = blockIdx.y*32;
  int tx = threadIdx.x & 31, ty = threadIdx.x >> 5;
  #pragma unroll
  for (int i=0;i<4;i++){
    int r = ty + i*8;
    tile[r][tx] = Wh[(size_t)h*D_MODEL*HDIM + (size_t)(d0+r)*HDIM + e0 + tx];
  }
  __syncthreads();
  #pragma unroll
  for (int i=0;i<4;i++){
    int r = ty + i*8;
    WT[(size_t)(h*HDIM + e0 + r)*D_MODEL + d0 + tx] = f2bf(tile[tx][r]);
  }
}

// --------- combined bias: bc[z*1024 + h*64+e] = dot(bz, Whz[h][:][e]) + bhz
__global__ __launch_bounds__(64) void bias_comb(
  const float* bk, const float* bq, const float* bv,
  const float* Whq, const float* Whk, const float* Whv,
  const float* bhq, const float* bhk, const float* bhv, float* bc)
{
  int blk = blockIdx.x; int which = blk >> 4; int h = blk & 15; int e = threadIdx.x;
  const float* bvec = (which==0) ? bk : (which==1) ? bq : bv;
  const float* Wh   = (which==0) ? Whq : (which==1) ? Whk : Whv;
  const float* bh   = (which==0) ? bhq : (which==1) ? bhk : bhv;
  float s = bh[h*HDIM + e];
  const float* w = Wh + (size_t)h*D_MODEL*HDIM + e;
  for (int d=0; d<D_MODEL; ++d) s += bvec[d] * w[(size_t)d*HDIM];
  bc[which*1024 + h*HDIM + e] = s;
}

// ============== 256x256 GEMM: burst-stage, 1 barrier/K-tile ===============
// BK=64, 8 waves (2M x 4N). Whole next K-tile staged at P0 (8 loads),
// vmcnt(8) -> full-K-tile lead (~3000cyc > HBM latency). One barrier per
// K-tile (P1-P3 write nothing -> no intra-tile hazards; reads of buf^1
// retired via lgkmcnt before previous barrier). B halves persist in regs.
__global__ __launch_bounds__(512,1) void gemm256_8p(
  const u16* __restrict__ A, const u16* __restrict__ BT, const float* __restrict__ bias,
  u16* __restrict__ outB, int N, int K, int mode, int act)
{
  __shared__ __align__(16) u16 As[2][2][128*64];
  __shared__ __align__(16) u16 Bs[2][2][128*64];
  int t = threadIdx.x, lane = t&63, wid = t>>6;
  int wr = wid>>2, wc = wid&3;
  int fr = lane&15, kg = lane>>4;
  int gx = gridDim.x;
  int bid = blockIdx.y*gx + blockIdx.x;
  int nwg = gx*gridDim.y;
  int cpx = nwg>>3;
  int sw = (bid&7)*cpx + (bid>>3);
  int tc = sw % gx, tr = sw / gx;

  const u16* Abase = A  + (size_t)tr*256*K;
  const u16* Bbase = BT + (size_t)tc*256*K;
  int srow = lane>>3, sch8 = lane&7;

  f32x4 acc[8][4];
  #pragma unroll
  for (int m=0;m<8;m++)
    #pragma unroll
    for (int n=0;n<4;n++) acc[m][n] = (f32x4)0.f;

  bf16x8v af[2][4], bv0[2][2], bv1[2][2];

  #define STAGE_A8(buf,h,kt) { _Pragma("unroll") for (int li=0;li<2;li++){ \
    int sr = (wid*2+li)*8 + srow; \
    int gr = ((sr>>6)<<7) + (h)*64 + (sr&63); \
    int sc = sch8 ^ (sr&7); \
    gload_lds16(Abase + (size_t)gr*K + (size_t)(kt)*64 + sc*8, &As[buf][h][(wid*2+li)*512]); } }
  #define STAGE_B8(buf,h,kt) { _Pragma("unroll") for (int li=0;li<2;li++){ \
    int sr = (wid*2+li)*8 + srow; \
    int gc = ((sr>>5)<<6) + (h)*32 + (sr&31); \
    int sc = sch8 ^ (sr&7); \
    gload_lds16(Bbase + (size_t)gc*K + (size_t)(kt)*64 + sc*8, &Bs[buf][h][(wid*2+li)*512]); } }
  #define STAGE_ALL(buf,kt) { STAGE_A8(buf,0,kt); STAGE_B8(buf,0,kt); STAGE_B8(buf,1,kt); STAGE_A8(buf,1,kt); }
  #define LDA8(buf,h) { _Pragma("unroll") for (int ks=0;ks<2;ks++) _Pragma("unroll") for (int mf=0;mf<4;mf++){ \
    int r = wr*64 + mf*16 + fr; \
    af[ks][mf] = *(const bf16x8v*)&As[buf][h][r*64 + (((kg+4*ks)^(r&7)))*8]; } }
  #define LDB8(buf,h,dst) { _Pragma("unroll") for (int ks=0;ks<2;ks++) _Pragma("unroll") for (int nf=0;nf<2;nf++){ \
    int r = wc*32 + nf*16 + fr; \
    dst[ks][nf] = *(const bf16x8v*)&Bs[buf][h][r*64 + (((kg+4*ks)^(r&7)))*8]; } }
  #define MM8(mq,nq,bv) { asm volatile("s_waitcnt lgkmcnt(0)" ::: "memory"); \
    __builtin_amdgcn_s_setprio(1); \
    _Pragma("unroll") for (int ks=0;ks<2;ks++) _Pragma("unroll") for (int mf=0;mf<4;mf++) _Pragma("unroll") for (int nf=0;nf<2;nf++) \
      acc[(mq)*4+mf][(nq)*2+nf] = __builtin_amdgcn_mfma_f32_16x16x32_bf16(af[ks][mf], bv[ks][nf], acc[(mq)*4+mf][(nq)*2+nf], 0,0,0); \
    __builtin_amdgcn_s_setprio(0); }
  #define BAR asm volatile("s_barrier" ::: "memory")

  int NT = K >> 6;
  STAGE_ALL(0,0);

  for (int kt=0; kt<NT; ++kt){
    int buf = kt&1, nb = buf^1;
    if (kt+1 < NT){
      STAGE_ALL(nb, kt+1);
      asm volatile("s_waitcnt vmcnt(8)" ::: "memory");
    } else {
      asm volatile("s_waitcnt vmcnt(0)" ::: "memory");
    }
    BAR;
    LDA8(buf,0); LDB8(buf,0,bv0); MM8(0,0,bv0);
    LDB8(buf,1,bv1);              MM8(0,1,bv1);
    LDA8(buf,1);                  MM8(1,1,bv1);
                                  MM8(1,0,bv0);
  }

  int crow0 = tr*256 + wr*128;
  int ccol0 = tc*256 + wc*64;
  #pragma unroll
  for (int n=0;n<4;n++){
    int col = ccol0 + n*16 + fr;
    float bv = bias[col];
    #pragma unroll
    for (int m=0;m<8;m++){
      int rbase = crow0 + m*16 + kg*4;
      #pragma unroll
      for (int i=0;i<4;i++){
        float v = acc[m][n][i] + bv;
        if (act) v = gelu_f(v);
        int row = rbase + i;
        if (mode == 1){
          outB[(size_t)row*N + col] = f2bf(v);
        } else {
          int panel = col >> 10, c1 = col & 1023;
          if (panel < 2)
            outB[(size_t)panel*((size_t)ROWS*1024) + (size_t)row*1024 + c1] = f2bf(v);
          else {
            int b = row >> 10, s = row & 1023;
            int hh = c1 >> 6, e = c1 & 63;
            outB[(size_t)2*((size_t)ROWS*1024) + (((size_t)((b*NHEAD+hh)*HDIM+e))<<10) + s] = f2bf(v);
          }
        }
      }
    }
  }
}

// ============ 128x128 tile, BK=32, 4 waves, 3-buffer 2-deep pipeline ======
__device__ __forceinline__ void stage128(u16 (*As)[4096], u16 (*Bs)[4096], int b,
  const u16* Ab, const u16* Bb, int Kstride, int kt, int wid, int rr, int sch)
{
  #pragma unroll
  for (int c=0;c<2;c++){
    int reg = c*4 + wid;
    int row = reg*16 + rr;
    gload_lds16(Ab + (size_t)row*Kstride + kt*32 + sch*8, &As[b][reg*512]);
  }
  #pragma unroll
  for (int c=0;c<2;c++){
    int reg = c*4 + wid;
    int row = reg*16 + rr;
    gload_lds16(Bb + (size_t)row*Kstride + kt*32 + sch*8, &Bs[b][reg*512]);
  }
}

__device__ __forceinline__ void gemm128_core(u16 (*As)[4096], u16 (*Bs)[4096],
  const u16* __restrict__ A, const u16* __restrict__ BT, const float* __restrict__ bias,
  float* __restrict__ outF, u16* __restrict__ outB,
  int N, int Kstride, int kofs, int Ksub, int mode, int act, int addbias)
{
  int t = threadIdx.x, lane = t&63, wid = t>>6;
  int wr = wid>>1, wc = wid&1;
  int fr = lane&15, kg = lane>>4;
  int gx = gridDim.x;
  int bid = blockIdx.y*gx + blockIdx.x;
  int nwg = gx*gridDim.y;
  int cpx = nwg >> 3;
  int sw = (bid&7)*cpx + (bid>>3);
  int tc = sw % gx, tr = sw / gx;

  const u16* Ab = A  + (size_t)tr*128*Kstride + kofs;
  const u16* Bb = BT + (size_t)tc*128*Kstride + kofs;
  int rr = lane>>2, cc = lane&3;
  int sch = cc ^ ((rr>>1)&3);

  f32x4 acc[4][4];
  #pragma unroll
  for (int m=0;m<4;m++)
    #pragma unroll
    for (int n=0;n<4;n++) acc[m][n] = (f32x4)0.f;

  int NT = Ksub >> 5;

  stage128(As, Bs, 0, Ab, Bb, Kstride, 0, wid, rr, sch);
  stage128(As, Bs, 1, Ab, Bb, Kstride, 1, wid, rr, sch);
  int buf = 0;
  for (int kt=0; kt<NT; ++kt){
    if (kt+2 < NT){
      int nb = buf+2; if (nb>=3) nb-=3;
      stage128(As, Bs, nb, Ab, Bb, Kstride, kt+2, wid, rr, sch);
      asm volatile("s_waitcnt vmcnt(8)" ::: "memory");
    } else if (kt+1 < NT){
      asm volatile("s_waitcnt vmcnt(4)" ::: "memory");
    } else {
      asm volatile("s_waitcnt vmcnt(0)" ::: "memory");
    }
    asm volatile("s_barrier" ::: "memory");
    bf16x8v af[4], bfv[4];
    #pragma unroll
    for (int m=0;m<4;m++){
      int r = wr*64 + m*16 + fr;
      af[m] = *(const bf16x8v*)&As[buf][r*32 + (kg ^ ((r>>1)&3))*8];
    }
    #pragma unroll
    for (int n=0;n<4;n++){
      int r = wc*64 + n*16 + fr;
      bfv[n] = *(const bf16x8v*)&Bs[buf][r*32 + (kg ^ ((r>>1)&3))*8];
    }
    #pragma unroll
    for (int m=0;m<4;m++)
      #pragma unroll
      for (int n=0;n<4;n++)
        acc[m][n] = __builtin_amdgcn_mfma_f32_16x16x32_bf16(af[m], bfv[n], acc[m][n], 0,0,0);
    if (kt+1 < NT)
      asm volatile("s_barrier" ::: "memory");
    buf += 1; if (buf >= 3) buf = 0;
  }

  int crow0 = tr*128 + wr*64;
  int ccol0 = tc*128 + wc*64;
  #pragma unroll
  for (int n=0;n<4;n++){
    int col = ccol0 + n*16 + fr;
    float bv = addbias ? bias[col] : 0.f;
    #pragma unroll
    for (int m=0;m<4;m++){
      int rbase = crow0 + m*16 + kg*4;
      #pragma unroll
      for (int i=0;i<4;i++){
        float v = acc[m][n][i] + bv;
        if (act) v = gelu_f(v);
        int row = rbase + i;
        if (mode == 1){
          outB[(size_t)row*N + col] = f2bf(v);
        } else {
          outF[(size_t)row*1024 + col] = v;
        }
      }
    }
  }
}

// split-K (2-way): z selects K-half; fp32 partial panels; bias on z==0
__global__ __launch_bounds__(256) void g_gemm_sk(
  const u16* A, const u16* BT, const float* bias, float* outBase, int K)
{
  __shared__ __align__(16) u16 As[3][4096];
  __shared__ __align__(16) u16 Bs[3][4096];
  int z = blockIdx.z;
  int Ksub = K >> 1;
  gemm128_core(As, Bs, A, BT, bias, outBase + (size_t)z*ROWS*1024, nullptr,
               1024, K, z*Ksub, Ksub, 3, 0, z==0);
}

struct B3 { const u16* A[3]; const u16* BT[3]; u16* Cb[3]; };
__global__ __launch_bounds__(256) void g_gemm_b3(B3 p, const float* bias){
  __shared__ __align__(16) u16 As[3][4096];
  __shared__ __align__(16) u16 Bs[3][4096];
  int z = blockIdx.z;
  gemm128_core(As, Bs, p.A[z], p.BT[z], bias, nullptr, p.Cb[z],
               1024, 1024, 0, 1024, 1, 0, 0);
}

// ====== MFMA flash attention (round-6 shell + exp2 softmax + defer-max) ===
// Block: one (b,h) x 64 q-rows, 4 waves x 16 rows. KV tile 64, single-buffer
// LDS (24KB -> 6 blocks/CU).
__global__ __launch_bounds__(256) void attn_mfma(const u16* __restrict__ Q, const u16* __restrict__ Km,
                                                 const u16* __restrict__ Vt, u16* __restrict__ O)
{
  __shared__ __align__(16) u16 Ks[64*64];
  __shared__ __align__(16) u16 Vs[64*64];
  __shared__ __align__(16) u16 Ps[4][16*64];
  int t = threadIdx.x, lane = t & 63, wid = t >> 6;
  int fr = lane & 15, kg = lane >> 4;
  int qt = blockIdx.x, h = blockIdx.y, b = blockIdx.z;
  const size_t qkbase = ((size_t)b*SEQ)*D_MODEL + (size_t)h*HDIM;
  const size_t vtb = ((size_t)(b*NHEAD + h))*HDIM*SEQ;

  int qrow = qt*64 + wid*16 + fr;
  bf16x8v aq0 = *(const bf16x8v*)(Q + qkbase + (size_t)qrow*D_MODEL + kg*8);
  bf16x8v aq1 = *(const bf16x8v*)(Q + qkbase + (size_t)qrow*D_MODEL + 32 + kg*8);

  f32x4 Oacc[4];
  #pragma unroll
  for (int n=0;n<4;n++) Oacc[n] = (f32x4)0.f;
  float m_run[4], l_run[4];
  #pragma unroll
  for (int i=0;i<4;i++){ m_run[i] = -3e38f; l_run[i] = 0.f; }

  int srow = lane >> 3;
  int sch  = (lane & 7) ^ srow;
  int x7 = fr & 7;
  const float CS = 0.03125f * 1.4426950408889634f;   // 1/sqrt(D) * log2(e)
  u16* Pw = &Ps[wid][0];

  for (int kt = 0; kt < SEQ/64; ++kt){
    __syncthreads();
    #pragma unroll
    for (int c=0;c<2;c++){
      int r0 = (wid*2 + c)*8;
      int rowk = r0 + srow;
      gload_lds16(Km + qkbase + (size_t)(kt*64 + rowk)*D_MODEL + sch*8, &Ks[r0*64]);
      gload_lds16(Vt + vtb + (size_t)rowk*SEQ + kt*64 + sch*8, &Vs[r0*64]);
    }
    asm volatile("s_waitcnt vmcnt(0)" ::: "memory");
    __syncthreads();

    // S = Q K^T (exp2-domain scale after)
    f32x4 s4[4];
    #pragma unroll
    for (int n=0;n<4;n++){
      int r = n*16 + fr;
      bf16x8v k0 = *(const bf16x8v*)&Ks[r*64 + ((kg  ) ^ x7)*8];
      bf16x8v k1 = *(const bf16x8v*)&Ks[r*64 + ((4+kg) ^ x7)*8];
      f32x4 z = (f32x4)0.f;
      z = __builtin_amdgcn_mfma_f32_16x16x32_bf16(aq0, k0, z, 0,0,0);
      s4[n] = __builtin_amdgcn_mfma_f32_16x16x32_bf16(aq1, k1, z, 0,0,0);
    }
    #pragma unroll
    for (int n=0;n<4;n++) s4[n] *= CS;

    // online softmax (exp2 domain, defer-max THR=8)
    float mI[4];
    #pragma unroll
    for (int i=0;i<4;i++)
      mI[i] = fmaxf(fmaxf(s4[0][i], s4[1][i]), fmaxf(s4[2][i], s4[3][i]));
    #pragma unroll
    for (int off=1; off<16; off<<=1){
      #pragma unroll
      for (int i=0;i<4;i++) mI[i] = fmaxf(mI[i], __shfl_xor(mI[i], off));
    }
    float g = -3e38f;
    #pragma unroll
    for (int i=0;i<4;i++) g = fmaxf(g, mI[i] - m_run[i]);
    if (__any(g > 8.f)){
      #pragma unroll
      for (int i=0;i<4;i++){
        float mn = fmaxf(m_run[i], mI[i]);
        float sc = exp2f(m_run[i] - mn);
        m_run[i] = mn;
        l_run[i] *= sc;
        #pragma unroll
        for (int n=0;n<4;n++) Oacc[n][i] *= sc;
      }
    }
    float ls[4] = {0.f,0.f,0.f,0.f};
    #pragma unroll
    for (int n=0;n<4;n++){
      int chunk = n*2 + (fr>>3);
      #pragma unroll
      for (int i=0;i<4;i++){
        float pv = exp2f(s4[n][i] - m_run[i]);
        ls[i] += pv;
        int row = kg*4 + i;
        Pw[row*64 + (chunk ^ (row&7))*8 + (fr&7)] = f2bf(pv);
      }
    }
    #pragma unroll
    for (int off=1; off<16; off<<=1){
      #pragma unroll
      for (int i=0;i<4;i++) ls[i] += __shfl_xor(ls[i], off);
    }
    #pragma unroll
    for (int i=0;i<4;i++) l_run[i] += ls[i];
    asm volatile("s_waitcnt lgkmcnt(0)" ::: "memory");

    // O += P V
    bf16x8v ap0 = *(const bf16x8v*)&Pw[fr*64 + ((kg  ) ^ x7)*8];
    bf16x8v ap1 = *(const bf16x8v*)&Pw[fr*64 + ((4+kg) ^ x7)*8];
    #pragma unroll
    for (int n2=0;n2<4;n2++){
      int r = n2*16 + fr;
      bf16x8v v0 = *(const bf16x8v*)&Vs[r*64 + ((kg  ) ^ x7)*8];
      bf16x8v v1 = *(const bf16x8v*)&Vs[r*64 + ((4+kg) ^ x7)*8];
      Oacc[n2] = __builtin_amdgcn_mfma_f32_16x16x32_bf16(ap0, v0, Oacc[n2], 0,0,0);
      Oacc[n2] = __builtin_amdgcn_mfma_f32_16x16x32_bf16(ap1, v1, Oacc[n2], 0,0,0);
    }
  }

  float inv[4];
  #pragma unroll
  for (int i=0;i<4;i++) inv[i] = 1.f / l_run[i];
  #pragma unroll
  for (int n2=0;n2<4;n2++){
    #pragma unroll
    for (int i=0;i<4;i++){
      int row = qt*64 + wid*16 + kg*4 + i;
      O[qkbase + (size_t)row*D_MODEL + n2*16 + fr] = f2bf(Oacc[n2][i]*inv[i]);
    }
  }
}

// -------- residual(3-way) + LayerNorm: v = A + B + C; LN(v) --------------
__global__ __launch_bounds__(256) void ln_sum3(const float* __restrict__ A, const float* __restrict__ B,
   const float* __restrict__ C, const float* __restrict__ gamma, const float* __restrict__ beta,
   float* __restrict__ Of, u16* __restrict__ Ob)
{
  int row = blockIdx.x, t = threadIdx.x;
  size_t base = (size_t)row*D_MODEL + t*4;
  f32x4 v = *(const f32x4*)(A + base);
  v += *(const f32x4*)(B + base);
  v += *(const f32x4*)(C + base);
  float s = v.x+v.y+v.z+v.w;
  float q = v.x*v.x+v.y*v.y+v.z*v.z+v.w*v.w;
  #pragma unroll
  for (int off=1; off<64; off<<=1){ s += __shfl_xor(s,off); q += __shfl_xor(q,off); }
  __shared__ float red[8];
  int wid = t>>6;
  if ((t&63)==0){ red[wid] = s; red[wid+4] = q; }
  __syncthreads();
  s = red[0]+red[1]+red[2]+red[3];
  q = red[4]+red[5]+red[6]+red[7];
  float mu = s*(1.f/1024.f);
  float var = q*(1.f/1024.f) - mu*mu;
  float rs = rsqrtf(var + 1e-5f);
  f32x4 g4 = *(const f32x4*)(gamma + t*4);
  f32x4 b4 = *(const f32x4*)(beta + t*4);
  f32x4 o;
  o.x = (v.x-mu)*rs*g4.x + b4.x;
  o.y = (v.y-mu)*rs*g4.y + b4.y;
  o.z = (v.z-mu)*rs*g4.z + b4.z;
  o.w = (v.w-mu)*rs*g4.w + b4.w;
  if (Of) *(f32x4*)(Of + base) = o;
  if (Ob){
    u16x4 ob = { f2bf(o.x), f2bf(o.y), f2bf(o.z), f2bf(o.w) };
    *(u16x4*)(Ob + base) = ob;
  }
}

extern "C" void kernel_launch(void* const* d_in, const int* in_sizes, int n_in,
                              void* d_out, int out_size, void* d_ws, size_t ws_size,
                              hipStream_t stream)
{
  const float* x    = (const float*)d_in[0];
  const float* Wk   = (const float*)d_in[1];
  const float* bk   = (const float*)d_in[2];
  const float* Wq   = (const float*)d_in[3];
  const float* bq   = (const float*)d_in[4];
  const float* Wv   = (const float*)d_in[5];
  const float* bv   = (const float*)d_in[6];
  const float* Whq  = (const float*)d_in[7];
  const float* bhq  = (const float*)d_in[8];
  const float* Whk  = (const float*)d_in[9];
  const float* bhk  = (const float*)d_in[10];
  const float* Whv  = (const float*)d_in[11];
  const float* bhv  = (const float*)d_in[12];
  const float* Wo   = (const float*)d_in[13];
  const float* bo   = (const float*)d_in[14];
  const float* W1   = (const float*)d_in[15];
  const float* b1   = (const float*)d_in[16];
  const float* W2   = (const float*)d_in[17];
  const float* b2   = (const float*)d_in[18];
  const float* gamma= (const float*)d_in[19];
  const float* beta = (const float*)d_in[20];

  char* ws = (char*)d_ws;
  const size_t MB_ = 1024*1024;
  u16* Wkb  = (u16*)(ws + 0*MB_);
  u16* Wqb  = (u16*)(ws + 2*MB_);
  u16* Wvb  = (u16*)(ws + 4*MB_);
  u16* WhqT = (u16*)(ws + 6*MB_);
  u16* WhkT = (u16*)(ws + 8*MB_);
  u16* WhvT = (u16*)(ws + 10*MB_);
  u16* WoT  = (u16*)(ws + 12*MB_);
  u16* W1T  = (u16*)(ws + 14*MB_);   // [4096][1024]
  u16* W2T  = (u16*)(ws + 22*MB_);   // [1024][4096]
  u16* xb   = (u16*)(ws + 30*MB_);   // 8MB
  u16* WcT  = (u16*)(ws + 38*MB_);   // 3 panels x 2MB
  float* bc = (float*)(ws + 44*MB_);
  u16* qb   = (u16*)(ws + 46*MB_);
  u16* kb   = (u16*)(ws + 54*MB_);
  u16* vt   = (u16*)(ws + 62*MB_);
  u16* Ob   = (u16*)(ws + 70*MB_);
  float* Pa = (float*)(ws + 78*MB_);
  float* Pb = (float*)(ws + 94*MB_);
  float* r1f = (float*)(ws + 110*MB_);
  u16*  r1b  = (u16*)(ws + 38*MB_);
  u16*  ff1b = (u16*)(ws + 46*MB_);

  dim3 tb(256);

  // ---- prep (merged dispatches) ----
  C4 cv; cv.src[0]=x; cv.src[1]=Wk; cv.src[2]=Wq; cv.src[3]=Wv;
  cv.dst[0]=xb; cv.dst[1]=Wkb; cv.dst[2]=Wqb; cv.dst[3]=Wvb;
  convert4<<<dim3(4096+3072), tb, 0, stream>>>(cv);
  H3 hh; hh.src[0]=Whq; hh.src[1]=Whk; hh.src[2]=Whv;
  hh.dst[0]=WhqT; hh.dst[1]=WhkT; hh.dst[2]=WhvT;
  head_transpose3<<<dim3(32,2,48), tb, 0, stream>>>(hh);
  T3 tt; tt.W[0]=Wo; tt.W[1]=W1; tt.W[2]=W2;
  tt.WT[0]=WoT; tt.WT[1]=W1T; tt.WT[2]=W2T;
  transpose3<<<dim3(9216), tb, 0, stream>>>(tt);
  bias_comb<<<dim3(48), dim3(64), 0, stream>>>(bk,bq,bv, Whq,Whk,Whv, bhq,bhk,bhv, bc);

  // ---- weight combine: WcT[z] = Wh[z]^T · Wouter[z]^T ----
  B3 cmb;
  cmb.A[0]=WhqT; cmb.A[1]=WhkT; cmb.A[2]=WhvT;
  cmb.BT[0]=Wkb; cmb.BT[1]=Wqb; cmb.BT[2]=Wvb;
  cmb.Cb[0]=WcT; cmb.Cb[1]=WcT+1048576; cmb.Cb[2]=WcT+2097152;
  g_gemm_b3<<<dim3(8,8,3), tb, 0, stream>>>(cmb, bk);

  // ---- fused QKV projection: x @ [Wcq|Wck|Wcv] + bc -> qb, kb, vt ----
  gemm256_8p<<<dim3(12,16), dim3(512), 0, stream>>>(xb, WcT, bc, qb, 3072, 1024, 2, 0);

  // ---- attention ----
  attn_mfma<<<dim3(16,16,4), tb, 0, stream>>>(qb, kb, vt, Ob);

  // ---- Wo: split-K x2 -> fp32 partials Pa,Pb ----
  g_gemm_sk<<<dim3(8,32,2), tb, 0, stream>>>(Ob, WoT, bo, Pa, 1024);
  ln_sum3<<<dim3(4096), tb, 0, stream>>>(x, Pa, Pb, gamma, beta, r1f, r1b);
  // ---- FFN1 (gelu) ----
  gemm256_8p<<<dim3(16,16), dim3(512), 0, stream>>>(r1b, W1T, b1, ff1b, 4096, 1024, 1, 1);
  // ---- FFN2: split-K x2 -> Pa,Pb ----
  g_gemm_sk<<<dim3(8,32,2), tb, 0, stream>>>(ff1b, W2T, b2, Pa, 4096);
  ln_sum3<<<dim3(4096), tb, 0, stream>>>(r1f, Pa, Pb, gamma, beta, (float*)d_out, nullptr);

  (void)in_sizes; (void)n_in; (void)out_size; (void)ws_size;
}